// Round 1
// baseline (268.139 us; speedup 1.0000x reference)
//
#include <hip/hip_runtime.h>
#include <stdint.h>

#define B_ 4
#define C_ 256
#define N_ 4096

typedef unsigned short u16;
typedef __attribute__((ext_vector_type(4))) float f32x4;
typedef __attribute__((ext_vector_type(8))) short bf16x8;
typedef __attribute__((ext_vector_type(4))) int i32x4;

__device__ __forceinline__ u16 f2bf(float f) {
    uint32_t u = __float_as_uint(f);
    u += 0x7fffu + ((u >> 16) & 1u);
    return (u16)(u >> 16);
}

// ---------------- Stage 0: W fp32 -> bf16 ----------------
__global__ __launch_bounds__(256) void wconv_kernel(
    const float* __restrict__ Wq, const float* __restrict__ Wk,
    const float* __restrict__ Wv, u16* __restrict__ Wb) {
    int id = blockIdx.x * 256 + threadIdx.x;            // 0..196607
    const float* src = (id < 65536) ? Wq : ((id < 131072) ? Wk : Wv);
    Wb[id] = f2bf(src[id & 65535]);
}

// ---------------- Stage 1: QKV projection ----------------
// Qt,Kt: [B][N][C] bf16 (c-contiguous). Vt: [B][C][N] bf16 (n-contiguous).
__global__ __launch_bounds__(256) void qkv_kernel(
    const float* __restrict__ x, const u16* __restrict__ Wb,
    const float* __restrict__ bq, const float* __restrict__ bk,
    const float* __restrict__ bv,
    u16* __restrict__ Qt, u16* __restrict__ Kt, u16* __restrict__ Vt) {
    const int XTS = 264;  // padded row stride (elements), 16B-aligned rows
    __shared__ __align__(16) u16 xT[64 * XTS];

    int b  = blockIdx.x >> 6;
    int n0 = (blockIdx.x & 63) << 6;
    int tid = threadIdx.x;
    int lane = tid & 63;
    int w = tid >> 6;
    int l15 = lane & 15;
    int q = lane >> 4;

    // stage xT: x[b][c][n0..n0+64) fp32 -> xT[n][c] bf16 (transpose)
    {
        int c  = tid >> 4;            // 0..15
        int nq = (tid & 15) << 2;     // 0,4,..60
        const float* xb = x + ((size_t)b * C_ + c) * N_ + n0 + nq;
        for (int p = 0; p < 16; ++p) {
            f32x4 v = *(const f32x4*)(xb + (size_t)16 * N_ * p);
            int cc = c + 16 * p;
            xT[(nq + 0) * XTS + cc] = f2bf(v[0]);
            xT[(nq + 1) * XTS + cc] = f2bf(v[1]);
            xT[(nq + 2) * XTS + cc] = f2bf(v[2]);
            xT[(nq + 3) * XTS + cc] = f2bf(v[3]);
        }
    }
    __syncthreads();

    for (int mat = 0; mat < 3; ++mat) {
        const u16* W = Wb + mat * 65536;
        f32x4 acc[4][4];
        for (int a = 0; a < 4; ++a)
            for (int c2 = 0; c2 < 4; ++c2)
                for (int r = 0; r < 4; ++r) acc[a][c2][r] = 0.f;

        for (int ks = 0; ks < 8; ++ks) {
            int cbase = 32 * ks + 8 * q;
            bf16x8 xfrag[4], wfrag[4];
            for (int t = 0; t < 4; ++t) {
                xfrag[t] = *(const bf16x8*)(&xT[(16 * t + l15) * XTS + cbase]);
                wfrag[t] = *(const bf16x8*)(W + (size_t)(64 * w + 16 * t + l15) * 256 + cbase);
            }
            if (mat < 2) {  // D[m=n][n'=o]: A=xT, B=W
                for (int mt = 0; mt < 4; ++mt)
                    for (int nt = 0; nt < 4; ++nt)
                        acc[mt][nt] = __builtin_amdgcn_mfma_f32_16x16x32_bf16(
                            xfrag[mt], wfrag[nt], acc[mt][nt], 0, 0, 0);
            } else {        // D[m=o][n'=n]: A=W, B=xT
                for (int mt = 0; mt < 4; ++mt)
                    for (int nt = 0; nt < 4; ++nt)
                        acc[mt][nt] = __builtin_amdgcn_mfma_f32_16x16x32_bf16(
                            wfrag[mt], xfrag[nt], acc[mt][nt], 0, 0, 0);
            }
        }

        if (mat < 2) {
            // col=l15 -> o = 64w+16nt+l15 ; row=4q+r -> n = 16mt+4q+r
            const float* bias = (mat == 0) ? bq : bk;
            u16* dst = (mat == 0) ? Qt : Kt;
            for (int nt = 0; nt < 4; ++nt) {
                int o = 64 * w + 16 * nt + l15;
                float bo = bias[o];
                for (int mt = 0; mt < 4; ++mt)
                    for (int r = 0; r < 4; ++r) {
                        int n = 16 * mt + 4 * q + r;
                        dst[((size_t)b * N_ + n0 + n) * C_ + o] = f2bf(acc[mt][nt][r] + bo);
                    }
            }
        } else {
            // col=l15 -> n = 16nt+l15 ; row -> o = 64w+16mt+4q+r
            for (int mt = 0; mt < 4; ++mt)
                for (int r = 0; r < 4; ++r) {
                    int o = 64 * w + 16 * mt + 4 * q + r;
                    float bo = bv[o];
                    for (int nt = 0; nt < 4; ++nt) {
                        int n = 16 * nt + l15;
                        Vt[((size_t)b * C_ + o) * N_ + n0 + n] = f2bf(acc[mt][nt][r] + bo);
                    }
                }
        }
    }
}

// ---------------- Stage 2: flash attention + residual ----------------
__global__ __launch_bounds__(256) void attn_kernel(
    const float* __restrict__ x, const u16* __restrict__ Qt,
    const u16* __restrict__ Kt, const u16* __restrict__ Vt,
    float* __restrict__ out) {
    const int KTS = 264;  // K tile row stride (64 rows of j, c-contiguous)
    const int VTS = 72;   // V tile row stride (256 rows of c, j-contiguous)
    const int PTS = 72;   // P row stride (64 rows of i, j-contiguous)
    __shared__ __align__(16) u16 Ksh[64 * KTS];
    __shared__ __align__(16) u16 Vsh[256 * VTS];
    __shared__ __align__(16) u16 Psh[64 * PTS];
    __shared__ float alphaSh[64];
    __shared__ float lSh[64];

    int b  = blockIdx.x >> 6;
    int i0 = (blockIdx.x & 63) << 6;
    int tid = threadIdx.x;
    int lane = tid & 63;
    int w = tid >> 6;
    int l15 = lane & 15;
    int q = lane >> 4;

    // Q fragments for this wave's softmax rows: i = i0 + 16w + l15, k=c
    bf16x8 qf[8];
    {
        const u16* qbase = Qt + ((size_t)b * N_ + i0 + 16 * w + l15) * C_ + 8 * q;
        for (int ks = 0; ks < 8; ++ks) qf[ks] = *(const bf16x8*)(qbase + 32 * ks);
    }

    float m_run = -1e30f;
    float l_run = 0.f;
    f32x4 oacc[4][4];  // [mt: c-subtile of wave's 64-c range][nt: i-subtile 0..3]
    for (int a = 0; a < 4; ++a)
        for (int c2 = 0; c2 < 4; ++c2)
            for (int r = 0; r < 4; ++r) oacc[a][c2][r] = 0.f;

    const float sconst = 0.0625f * 1.44269504088896340736f;  // (1/sqrt(C))*log2(e)
    const u16* Kb = Kt + (size_t)b * N_ * C_;
    const u16* Vb = Vt + (size_t)b * C_ * N_;

    for (int j0 = 0; j0 < N_; j0 += 64) {
        __syncthreads();
        {   // stage K tile: Kt rows j0..j0+64 (each 512B, contiguous)
            int row = tid >> 5;
            int off = (tid & 31) * 8;
            const u16* g = Kb + (size_t)(j0 + row) * C_ + off;
            u16* dst = Ksh + row * KTS + off;
            for (int p = 0; p < 8; ++p)
                *(i32x4*)(dst + (size_t)8 * KTS * p) = *(const i32x4*)(g + (size_t)8 * C_ * p);
        }
        {   // stage V tile: 256 rows of c, 128B each
            int row = tid >> 3;
            int off = (tid & 7) * 8;
            const u16* g = Vb + (size_t)row * N_ + j0 + off;
            u16* dst = Vsh + row * VTS + off;
            for (int p = 0; p < 8; ++p)
                *(i32x4*)(dst + (size_t)32 * VTS * p) = *(const i32x4*)(g + (size_t)32 * N_ * p);
        }
        __syncthreads();

        // QK^T (transposed): St[m=j][n'=i], wave's i-range = 16w
        f32x4 st[4];
        for (int mj = 0; mj < 4; ++mj)
            for (int r = 0; r < 4; ++r) st[mj][r] = 0.f;
        for (int ks = 0; ks < 8; ++ks) {
            int cb = 32 * ks + 8 * q;
            for (int mj = 0; mj < 4; ++mj) {
                bf16x8 kf = *(const bf16x8*)(&Ksh[(16 * mj + l15) * KTS + cb]);
                st[mj] = __builtin_amdgcn_mfma_f32_16x16x32_bf16(kf, qf[ks], st[mj], 0, 0, 0);
            }
        }

        // online softmax: i = lane&15 (per-lane state), j spread over regs+quads
        float t[4][4];
        float vmax = -1e30f;
        for (int mj = 0; mj < 4; ++mj)
            for (int r = 0; r < 4; ++r) {
                t[mj][r] = st[mj][r] * sconst;
                vmax = fmaxf(vmax, t[mj][r]);
            }
        vmax = fmaxf(vmax, __shfl_xor(vmax, 16));
        vmax = fmaxf(vmax, __shfl_xor(vmax, 32));
        float m_new = fmaxf(m_run, vmax);
        float alpha = exp2f(m_run - m_new);
        m_run = m_new;
        float psum = 0.f;
        u16 pb[4][4];
        for (int mj = 0; mj < 4; ++mj)
            for (int r = 0; r < 4; ++r) {
                float p = exp2f(t[mj][r] - m_new);
                psum += p;
                pb[mj][r] = f2bf(p);
            }
        psum += __shfl_xor(psum, 16);
        psum += __shfl_xor(psum, 32);
        l_run = l_run * alpha + psum;
        if (lane < 16) alphaSh[16 * w + lane] = alpha;
        // P write: row i = 16w+l15, col j = 16mj+4q+r
        for (int mj = 0; mj < 4; ++mj)
            for (int r = 0; r < 4; ++r)
                Psh[(16 * w + l15) * PTS + 16 * mj + 4 * q + r] = pb[mj][r];
        __syncthreads();

        // PV: O'[m=c][n'=i], wave's c-range = 64w, all i
        float av[4];
        for (int nt = 0; nt < 4; ++nt) av[nt] = alphaSh[16 * nt + l15];
        for (int mt = 0; mt < 4; ++mt)
            for (int nt = 0; nt < 4; ++nt)
                for (int r = 0; r < 4; ++r) oacc[mt][nt][r] *= av[nt];
        for (int ks2 = 0; ks2 < 2; ++ks2) {
            int jb = 32 * ks2 + 8 * q;
            bf16x8 pf[4];
            for (int nt = 0; nt < 4; ++nt)
                pf[nt] = *(const bf16x8*)(&Psh[(16 * nt + l15) * PTS + jb]);
            for (int mt = 0; mt < 4; ++mt) {
                bf16x8 vf = *(const bf16x8*)(&Vsh[(64 * w + 16 * mt + l15) * VTS + jb]);
                for (int nt = 0; nt < 4; ++nt)
                    oacc[mt][nt] = __builtin_amdgcn_mfma_f32_16x16x32_bf16(vf, pf[nt], oacc[mt][nt], 0, 0, 0);
            }
        }
    }

    __syncthreads();
    if (lane < 16) lSh[16 * w + lane] = l_run;
    __syncthreads();

    // epilogue: c = 64w+16mt+4q+r, i = i0+16nt+l15; coalesced along N
    for (int nt = 0; nt < 4; ++nt) {
        float rl = 1.0f / lSh[16 * nt + l15];
        int i = i0 + 16 * nt + l15;
        for (int mt = 0; mt < 4; ++mt) {
            int c = 64 * w + 16 * mt + 4 * q;
            for (int r = 0; r < 4; ++r) {
                size_t idx = ((size_t)b * C_ + (c + r)) * N_ + i;
                out[idx] = oacc[mt][nt][r] * rl + x[idx];
            }
        }
    }
}

extern "C" void kernel_launch(void* const* d_in, const int* in_sizes, int n_in,
                              void* d_out, int out_size, void* d_ws, size_t ws_size,
                              hipStream_t stream) {
    const float* x  = (const float*)d_in[0];
    const float* Wq = (const float*)d_in[1];
    const float* bq = (const float*)d_in[2];
    const float* Wk = (const float*)d_in[3];
    const float* bk = (const float*)d_in[4];
    const float* Wv = (const float*)d_in[5];
    const float* bv = (const float*)d_in[6];
    float* out = (float*)d_out;

    u16* Wb = (u16*)d_ws;                       // 3 * 256*256 bf16
    u16* Qt = Wb + 3 * 65536;                   // [B][N][C]
    u16* Kt = Qt + (size_t)B_ * N_ * C_;        // [B][N][C]
    u16* Vt = Kt + (size_t)B_ * N_ * C_;        // [B][C][N]

    wconv_kernel<<<768, 256, 0, stream>>>(Wq, Wk, Wv, Wb);
    qkv_kernel<<<256, 256, 0, stream>>>(x, Wb, bq, bk, bv, Qt, Kt, Vt);
    attn_kernel<<<256, 256, 0, stream>>>(x, Qt, Kt, Vt, out);
}

// Round 3
// 206.071 us; speedup vs baseline: 1.3012x; 1.3012x over previous
//
#include <hip/hip_runtime.h>
#include <stdint.h>

#define B_ 4
#define C_ 256
#define N_ 4096
#define JS 4          // j-splits

typedef unsigned short u16;
typedef __attribute__((ext_vector_type(4))) float f32x4;
typedef __attribute__((ext_vector_type(16))) float f32x16;
typedef __attribute__((ext_vector_type(8))) short bf16x8;
typedef __attribute__((ext_vector_type(4))) int i32x4;

__device__ __forceinline__ u16 f2bf(float f) {
    uint32_t u = __float_as_uint(f);
    u += 0x7fffu + ((u >> 16) & 1u);
    return (u16)(u >> 16);
}
__device__ __forceinline__ float bf2f(u16 v) {
    uint32_t u = ((uint32_t)v) << 16;
    return __uint_as_float(u);
}
// pack two fp32 -> bf16 pair (round-half-up), lo in low 16
__device__ __forceinline__ uint32_t pkbf(float a, float b) {
    uint32_t ua = __float_as_uint(a) + 0x8000u;
    uint32_t ub = __float_as_uint(b) + 0x8000u;
    return (ua >> 16) | (ub & 0xffff0000u);
}

// ---------------- Stage 0: W fp32 -> bf16 ----------------
__global__ __launch_bounds__(256) void wconv_kernel(
    const float* __restrict__ Wq, const float* __restrict__ Wk,
    const float* __restrict__ Wv, u16* __restrict__ Wb) {
    int id = blockIdx.x * 256 + threadIdx.x;            // 0..196607
    const float* src = (id < 65536) ? Wq : ((id < 131072) ? Wk : Wv);
    Wb[id] = f2bf(src[id & 65535]);
}

// ---------------- Stage 1: QKV projection (one matrix per block) ----------------
// Qt,Kt: [B][N][C] bf16 (c-contiguous). Vt: [B][C][N] bf16 (n-contiguous).
__global__ __launch_bounds__(256) void qkv_kernel(
    const float* __restrict__ x, const u16* __restrict__ Wb,
    const float* __restrict__ bq, const float* __restrict__ bk,
    const float* __restrict__ bv,
    u16* __restrict__ Qt, u16* __restrict__ Kt, u16* __restrict__ Vt) {
    const int XTS = 264;
    __shared__ __align__(16) u16 xT[64 * XTS];

    int blk = blockIdx.x;
    int n0  = (blk & 63) << 6;
    int b   = (blk >> 6) & 3;
    int mat = blk >> 8;              // 0=Q 1=K 2=V
    int tid = threadIdx.x;
    int lane = tid & 63;
    int w = tid >> 6;
    int l15 = lane & 15;
    int q = lane >> 4;

    {   // stage xT: x[b][c][n0..n0+64) fp32 -> xT[n][c] bf16 (transpose)
        int c  = tid >> 4;
        int nq = (tid & 15) << 2;
        const float* xb = x + ((size_t)b * C_ + c) * N_ + n0 + nq;
        for (int p = 0; p < 16; ++p) {
            f32x4 v = *(const f32x4*)(xb + (size_t)16 * N_ * p);
            int cc = c + 16 * p;
            xT[(nq + 0) * XTS + cc] = f2bf(v[0]);
            xT[(nq + 1) * XTS + cc] = f2bf(v[1]);
            xT[(nq + 2) * XTS + cc] = f2bf(v[2]);
            xT[(nq + 3) * XTS + cc] = f2bf(v[3]);
        }
    }
    __syncthreads();

    const u16* W = Wb + mat * 65536;
    f32x4 acc[4][4];
    for (int a = 0; a < 4; ++a)
        for (int c2 = 0; c2 < 4; ++c2)
            for (int r = 0; r < 4; ++r) acc[a][c2][r] = 0.f;

    for (int ks = 0; ks < 8; ++ks) {
        int cbase = 32 * ks + 8 * q;
        bf16x8 xfrag[4], wfrag[4];
        for (int t = 0; t < 4; ++t) {
            xfrag[t] = *(const bf16x8*)(&xT[(16 * t + l15) * XTS + cbase]);
            wfrag[t] = *(const bf16x8*)(W + (size_t)(64 * w + 16 * t + l15) * 256 + cbase);
        }
        if (mat < 2) {  // D[m=n][n'=o]
            for (int mt = 0; mt < 4; ++mt)
                for (int nt = 0; nt < 4; ++nt)
                    acc[mt][nt] = __builtin_amdgcn_mfma_f32_16x16x32_bf16(
                        xfrag[mt], wfrag[nt], acc[mt][nt], 0, 0, 0);
        } else {        // D[m=o][n'=n]
            for (int mt = 0; mt < 4; ++mt)
                for (int nt = 0; nt < 4; ++nt)
                    acc[mt][nt] = __builtin_amdgcn_mfma_f32_16x16x32_bf16(
                        wfrag[mt], xfrag[nt], acc[mt][nt], 0, 0, 0);
        }
    }

    if (mat < 2) {
        const float* bias = (mat == 0) ? bq : bk;
        u16* dst = (mat == 0) ? Qt : Kt;
        for (int nt = 0; nt < 4; ++nt) {
            int o = 64 * w + 16 * nt + l15;
            float bo = bias[o];
            for (int mt = 0; mt < 4; ++mt)
                for (int r = 0; r < 4; ++r) {
                    int n = 16 * mt + 4 * q + r;
                    dst[((size_t)b * N_ + n0 + n) * C_ + o] = f2bf(acc[mt][nt][r] + bo);
                }
        }
    } else {
        for (int mt = 0; mt < 4; ++mt)
            for (int r = 0; r < 4; ++r) {
                int o = 64 * w + 16 * mt + 4 * q + r;
                float bo = bv[o];
                for (int nt = 0; nt < 4; ++nt) {
                    int n = 16 * nt + l15;
                    Vt[((size_t)b * C_ + o) * N_ + n0 + n] = f2bf(acc[mt][nt][r] + bo);
                }
            }
    }
}

// ---------------- Stage 2: flash attention, split-j, 32x32x16 MFMA ----------------
// Grid: 512 = 32 i-tiles(128) x 4 b x 4 splits. Block 256 thr = 4 waves x 32 i-rows.
// Writes unnormalized partial O (bf16) + per-row (m,l) fp32.
__global__ __launch_bounds__(256, 2) void attn_kernel(
    const u16* __restrict__ Qt, const u16* __restrict__ Kt,
    const u16* __restrict__ Vt, u16* __restrict__ Op,
    float* __restrict__ mArr, float* __restrict__ lArr) {
    const int KTS = 264;   // 64 j-rows x 256 c (+pad)
    const int VTS = 72;    // 256 c-rows x 64 j (+pad)
    __shared__ __align__(16) u16 Ksh[64 * KTS];
    __shared__ __align__(16) u16 Vsh[256 * VTS];

    int blk = blockIdx.x;
    int it = blk & 31;
    int b  = (blk >> 5) & 3;
    int s  = blk >> 7;
    int i0 = it << 7;
    int tid = threadIdx.x;
    int lane = tid & 63;
    int w = tid >> 6;
    int l31 = lane & 31;
    int h = lane >> 5;

    // Q B-frags: n=i=l31 (wave strip i0+32w..), k=c=16ks+8h+e
    bf16x8 qf[16];
    {
        const u16* qrow = Qt + ((size_t)b * N_ + i0 + 32 * w + l31) * C_ + 8 * h;
        #pragma unroll
        for (int ks = 0; ks < 16; ++ks) qf[ks] = *(const bf16x8*)(qrow + 16 * ks);
    }

    f32x16 oacc[8];
    #pragma unroll
    for (int mt = 0; mt < 8; ++mt)
        #pragma unroll
        for (int r = 0; r < 16; ++r) oacc[mt][r] = 0.f;
    float m_run = -1e30f, l_run = 0.f;

    const float sconst = 0.0625f * 1.44269504088896340736f;  // (1/sqrt C)*log2 e
    const u16* Kb = Kt + (size_t)b * N_ * C_;
    const u16* Vb = Vt + (size_t)b * C_ * N_;

    for (int jt = 0; jt < N_ / (64 * JS); ++jt) {
        int j0 = s * (N_ / JS) + jt * 64;
        __syncthreads();
        {   // stage K tile: rows j (64), 512B each
            int row = tid >> 5;
            int off = (tid & 31) * 8;
            const u16* g = Kb + (size_t)(j0 + row) * C_ + off;
            u16* dst = Ksh + row * KTS + off;
            #pragma unroll
            for (int p = 0; p < 8; ++p)
                *(i32x4*)(dst + (size_t)8 * KTS * p) = *(const i32x4*)(g + (size_t)8 * C_ * p);
        }
        {   // stage V tile: rows c (256), 128B each
            int row = tid >> 3;
            int off = (tid & 7) * 8;
            const u16* g = Vb + (size_t)row * N_ + j0 + off;
            u16* dst = Vsh + row * VTS + off;
            #pragma unroll
            for (int p = 0; p < 8; ++p)
                *(i32x4*)(dst + (size_t)32 * VTS * p) = *(const i32x4*)(g + (size_t)32 * N_ * p);
        }
        __syncthreads();

        // S^T = K·Q^T : D[m=j][n=i], two 32-row j-tiles
        f32x16 st0, st1;
        #pragma unroll
        for (int r = 0; r < 16; ++r) { st0[r] = 0.f; st1[r] = 0.f; }
        #pragma unroll
        for (int ks = 0; ks < 16; ++ks) {
            bf16x8 kf0 = *(const bf16x8*)(&Ksh[l31 * KTS + 16 * ks + 8 * h]);
            bf16x8 kf1 = *(const bf16x8*)(&Ksh[(32 + l31) * KTS + 16 * ks + 8 * h]);
            st0 = __builtin_amdgcn_mfma_f32_32x32x16_bf16(kf0, qf[ks], st0, 0, 0, 0);
            st1 = __builtin_amdgcn_mfma_f32_32x32x16_bf16(kf1, qf[ks], st1, 0, 0, 0);
        }

        // online softmax, per-lane row state (i = l31; partner lane = l^32)
        float vmax = st0[0];
        #pragma unroll
        for (int r = 1; r < 16; ++r) vmax = fmaxf(vmax, st0[r]);
        #pragma unroll
        for (int r = 0; r < 16; ++r) vmax = fmaxf(vmax, st1[r]);
        vmax = fmaxf(vmax, __shfl_xor(vmax, 32));
        float m_new = fmaxf(m_run, vmax * sconst);
        float alpha = exp2f(m_run - m_new);
        m_run = m_new;

        float psum = 0.f;
        uint32_t pd[16];  // [u=mj*4+g][d] packed bf16 pairs
        #pragma unroll
        for (int u = 0; u < 8; ++u) {
            const f32x16& stv = (u < 4) ? st0 : st1;
            int g = u & 3;
            #pragma unroll
            for (int d = 0; d < 2; ++d) {
                float p0 = exp2f(fmaf(stv[4 * g + 2 * d + 0], sconst, -m_new));
                float p1 = exp2f(fmaf(stv[4 * g + 2 * d + 1], sconst, -m_new));
                psum += p0 + p1;
                pd[u * 2 + d] = pkbf(p0, p1);
            }
        }
        psum += __shfl_xor(psum, 32);
        l_run = l_run * alpha + psum;

        // P: C/D layout -> B-operand frags via lane^32 quad exchange
        bf16x8 pf[4];
        #pragma unroll
        for (int ks2 = 0; ks2 < 4; ++ks2) {
            uint32_t oA0 = pd[4 * ks2 + 0], oA1 = pd[4 * ks2 + 1];  // u=2ks2   (h_s=0 role)
            uint32_t oB0 = pd[4 * ks2 + 2], oB1 = pd[4 * ks2 + 3];  // u=2ks2+1 (h_s=1 role)
            uint32_t sn0 = h ? oA0 : oB0, sn1 = h ? oA1 : oB1;      // what partner needs
            uint32_t rc0 = (uint32_t)__shfl_xor((int)sn0, 32);
            uint32_t rc1 = (uint32_t)__shfl_xor((int)sn1, 32);
            uint32_t ow0 = h ? oB0 : oA0, ow1 = h ? oB1 : oA1;      // own u=2ks2+h
            i32x4 fr;
            fr[0] = (int)(h ? rc0 : ow0);  // e0..1 (from h_s=0 lane)
            fr[1] = (int)(h ? rc1 : ow1);  // e2..3
            fr[2] = (int)(h ? ow0 : rc0);  // e4..5 (from h_s=1 lane)
            fr[3] = (int)(h ? ow1 : rc1);  // e6..7
            pf[ks2] = *(bf16x8*)&fr;
        }

        // rescale O (skip when no lane's max moved)
        if (__ballot(alpha < 1.0f)) {
            #pragma unroll
            for (int mt = 0; mt < 8; ++mt)
                #pragma unroll
                for (int r = 0; r < 16; ++r) oacc[mt][r] *= alpha;
        }

        // O += V·P : D[m=c][n=i]
        #pragma unroll
        for (int ks2 = 0; ks2 < 4; ++ks2) {
            #pragma unroll
            for (int mt = 0; mt < 8; ++mt) {
                bf16x8 vf = *(const bf16x8*)(&Vsh[(32 * mt + l31) * VTS + 16 * ks2 + 8 * h]);
                oacc[mt] = __builtin_amdgcn_mfma_f32_32x32x16_bf16(vf, pf[ks2], oacc[mt], 0, 0, 0);
            }
        }
    }

    // epilogue: write unnormalized partial O + (m,l)
    int i = i0 + 32 * w + l31;
    u16* ob = Op + ((size_t)(s * B_ + b) * C_) * N_ + i;
    #pragma unroll
    for (int mt = 0; mt < 8; ++mt)
        #pragma unroll
        for (int g = 0; g < 4; ++g)
            #pragma unroll
            for (int r = 0; r < 4; ++r) {
                int c = 32 * mt + 8 * g + r + 4 * h;
                ob[(size_t)c * N_] = f2bf(oacc[mt][4 * g + r]);
            }
    if (h == 0) {
        mArr[(size_t)(s * B_ + b) * N_ + i] = m_run;
        lArr[(size_t)(s * B_ + b) * N_ + i] = l_run;
    }
}

// ---------------- Stage 3: merge splits + residual ----------------
__global__ __launch_bounds__(256) void merge_kernel(
    const float* __restrict__ x, const u16* __restrict__ Op,
    const float* __restrict__ mArr, const float* __restrict__ lArr,
    float* __restrict__ out) {
    int blk = blockIdx.x;          // 512 = 2 c-halves x 64 i-chunks x 4 b
    int ch = blk & 1;
    int ib = (blk >> 1) & 63;
    int b  = blk >> 7;
    int i  = ib * 64 + (threadIdx.x & 63);
    int csub = threadIdx.x >> 6;   // 0..3

    float ms[JS], w_[JS];
    float M = -1e30f;
    #pragma unroll
    for (int s = 0; s < JS; ++s) {
        ms[s] = mArr[(size_t)(s * B_ + b) * N_ + i];
        M = fmaxf(M, ms[s]);
    }
    float L = 0.f;
    #pragma unroll
    for (int s = 0; s < JS; ++s) {
        w_[s] = exp2f(ms[s] - M);
        L += w_[s] * lArr[(size_t)(s * B_ + b) * N_ + i];
    }
    float rL = 1.0f / L;

    for (int cc = 0; cc < 32; ++cc) {
        int c = ch * 128 + csub * 32 + cc;
        size_t xi = ((size_t)b * C_ + c) * N_ + i;
        float acc = 0.f;
        #pragma unroll
        for (int s = 0; s < JS; ++s)
            acc += w_[s] * bf2f(Op[((size_t)(s * B_ + b) * C_ + c) * N_ + i]);
        out[xi] = fmaf(acc, rL, x[xi]);
    }
}

extern "C" void kernel_launch(void* const* d_in, const int* in_sizes, int n_in,
                              void* d_out, int out_size, void* d_ws, size_t ws_size,
                              hipStream_t stream) {
    const float* x  = (const float*)d_in[0];
    const float* Wq = (const float*)d_in[1];
    const float* bq = (const float*)d_in[2];
    const float* Wk = (const float*)d_in[3];
    const float* bk = (const float*)d_in[4];
    const float* Wv = (const float*)d_in[5];
    const float* bv = (const float*)d_in[6];
    float* out = (float*)d_out;

    u16* Wb = (u16*)d_ws;                         // 196608 u16
    u16* Qt = Wb + 3 * 65536;                     // [B][N][C]
    u16* Kt = Qt + (size_t)B_ * N_ * C_;          // [B][N][C]
    u16* Vt = Kt + (size_t)B_ * N_ * C_;          // [B][C][N]
    u16* Op = Vt + (size_t)B_ * N_ * C_;          // [JS][B][C][N] bf16 partials
    float* mArr = (float*)(Op + (size_t)JS * B_ * C_ * N_);
    float* lArr = mArr + (size_t)JS * B_ * N_;

    wconv_kernel<<<768, 256, 0, stream>>>(Wq, Wk, Wv, Wb);
    qkv_kernel<<<768, 256, 0, stream>>>(x, Wb, bq, bk, bv, Qt, Kt, Vt);
    attn_kernel<<<512, 256, 0, stream>>>(Qt, Kt, Vt, Op, mArr, lArr);
    merge_kernel<<<512, 256, 0, stream>>>(x, Op, mArr, lArr, out);
}